// Round 12
// baseline (666.237 us; speedup 1.0000x reference)
//
#include <hip/hip_runtime.h>
#include <hip/hip_cooperative_groups.h>
#include <hip/hip_bf16.h>
#include <math.h>

namespace cg = cooperative_groups;
using bf16 = __hip_bfloat16;

#define B_ 2
#define N_ 2048
#define H_ 8
#define DH_ 32
#define D_ 256

typedef short bf16x8 __attribute__((ext_vector_type(8)));
typedef float f32x4  __attribute__((ext_vector_type(4)));

static __device__ __forceinline__ unsigned short f2bu(float v){
  bf16 b = __float2bfloat16(v);
  unsigned short u; __builtin_memcpy(&u, &b, 2); return u;
}
// pack two floats -> bf16 pair (lo in low16)
static __device__ __forceinline__ unsigned pk2(float lo, float hi){
  return __builtin_amdgcn_perm(__float_as_uint(hi) + 0x8000u,
                               __float_as_uint(lo) + 0x8000u, 0x07060302u);
}
// exact-RNE pack (prologue/weights)
static __device__ __forceinline__ unsigned pkw(float lo, float hi){
  return (unsigned)f2bu(lo) | ((unsigned)f2bu(hi) << 16);
}

// ---------------- fused prep: xcast (0..1023) | wpack (1024..1279) | rope tables (1280..1407) ----------------
__global__ __launch_bounds__(256) void k_prep(const float* __restrict__ x,
    const float* __restrict__ Wq, const float* __restrict__ Wk,
    const float* __restrict__ Wv, const float* __restrict__ Wo,
    unsigned short* __restrict__ xb, unsigned short* __restrict__ wb,
    float* __restrict__ cosT, float* __restrict__ sinT){
  int bx = blockIdx.x, tid = threadIdx.x;
  if(bx < 1024){
    size_t g = (size_t)bx*256 + tid;
    float4 f = *(const float4*)(x + g*4);
    uint2 u; u.x = pk2(f.x, f.y); u.y = pk2(f.z, f.w);
    *(uint2*)(xb + g*4) = u;
  } else if(bx < 1280){
    int g = (bx - 1024)*256 + tid;
    int mat = g >> 14;
    int off = (g & 16383) * 4;
    const float* W = (mat==0)?Wq:(mat==1)?Wk:(mat==2)?Wv:Wo;
    float4 f = *(const float4*)(W + off);
    uint2 u; u.x = pkw(f.x, f.y); u.y = pkw(f.z, f.w);
    *(uint2*)(wb + (size_t)mat*65536 + off) = u;
  } else {
    int idx = (bx - 1280)*256 + tid;
    int n = idx >> 4, f = idx & 15;
    double invf = exp(-((double)(2*f)/32.0) * log(10000.0));
    double ang = (double)n * invf;
    cosT[idx] = (float)cos(ang);
    sinT[idx] = (float)sin(ang);
  }
}

// ---------------- unified MFMA GEMM (64-row form): 0=Q(RoPE) 1=K(RoPE) 2=V^T 3=proj ----------------
__global__ __launch_bounds__(256) void k_gemm(const unsigned short* __restrict__ a_in,
    const unsigned short* __restrict__ wball, const float* __restrict__ cosT,
    const float* __restrict__ sinT, unsigned short* __restrict__ qb,
    unsigned short* __restrict__ kb, unsigned short* __restrict__ vtb,
    float* __restrict__ fout, int mode_base){
  __shared__ __align__(16) unsigned xs[64*132];
  int tid = threadIdx.x;
  int w = tid >> 6, lane = tid & 63, q = lane >> 4, c = lane & 15;
  int mode = mode_base + blockIdx.y;
  int row0 = blockIdx.x * 64;
  const unsigned short* wbm = wball + (size_t)((mode < 3) ? mode : 3)*65536;
  for(int e = tid; e < 2048; e += 256){
    int row = e >> 5, ch = e & 31;
    uint4 u = *(const uint4*)(a_in + (size_t)(row0+row)*256 + ch*8);
    *(uint4*)&xs[row*132 + ch*4] = u;
  }
  __syncthreads();
  f32x4 acc[4][4];
  #pragma unroll
  for(int a=0;a<4;a++)
    #pragma unroll
    for(int b2=0;b2<4;b2++) acc[a][b2] = (f32x4){0.f,0.f,0.f,0.f};
  for(int kk = 0; kk < 8; kk++){
    bf16x8 af[4], bfr[4];
    #pragma unroll
    for(int RT=0;RT<4;RT++) af[RT] = *(bf16x8*)&xs[(RT*16+c)*132 + kk*16 + q*4];
    #pragma unroll
    for(int CT=0;CT<4;CT++){
      int ocol = w*64 + CT*16 + c;
      bfr[CT] = *(const bf16x8*)(wbm + (size_t)ocol*256 + kk*32 + q*8);
    }
    #pragma unroll
    for(int RT=0;RT<4;RT++)
      #pragma unroll
      for(int CT=0;CT<4;CT++)
        acc[RT][CT] = __builtin_amdgcn_mfma_f32_16x16x32_bf16(af[RT], bfr[CT], acc[RT][CT], 0, 0, 0);
  }
  int bb = row0 >> 11, nloc0 = row0 & (N_-1);
  if(mode < 2){                 // Q or K with RoPE, out [bh][n][dh] bf16
    unsigned short* dst = (mode == 0) ? qb : kb;
    #pragma unroll
    for(int hp = 0; hp < 2; hp++){
      size_t bh = (size_t)bb*H_ + 2*w + hp;
      #pragma unroll
      for(int RT=0;RT<4;RT++)
        #pragma unroll
        for(int r=0;r<4;r++){
          int n = nloc0 + RT*16 + q*4 + r;
          float cs = cosT[n*16 + c], sn = sinT[n*16 + c];
          float d0 = acc[RT][hp*2][r], d1 = acc[RT][hp*2+1][r];
          float n0v = d0*cs - d1*sn;
          float n1v = d1*cs + d0*sn;
          float p0 = __shfl_xor(n0v, 1, 64);
          float p1 = __shfl_xor(n1v, 1, 64);
          if((c & 1) == 0){
            size_t idx = (bh*N_ + n)*32;
            *(unsigned*)(dst + idx + c)      = pk2(n0v, p0);
            *(unsigned*)(dst + idx + 16 + c) = pk2(n1v, p1);
          }
        }
    }
  } else if(mode == 2){         // V transposed: [bh][dh][n] bf16
    #pragma unroll
    for(int CT=0;CT<4;CT++){
      int h = 2*w + (CT>>1), dh = (CT&1)*16 + c;
      size_t basev = ((size_t)(bb*H_ + h)*32 + dh)*N_;
      #pragma unroll
      for(int RT=0;RT<4;RT++){
        int n = nloc0 + RT*16 + q*4;
        uint2 u;
        u.x = pk2(acc[RT][CT][0], acc[RT][CT][1]);
        u.y = pk2(acc[RT][CT][2], acc[RT][CT][3]);
        *(uint2*)(vtb + basev + n) = u;
      }
    }
  } else {                      // proj: fp32 out [row][ocol]
    #pragma unroll
    for(int RT=0;RT<4;RT++)
      #pragma unroll
      for(int r=0;r<4;r++){
        size_t row = (size_t)row0 + RT*16 + q*4 + r;
        #pragma unroll
        for(int CT=0;CT<4;CT++)
          fout[row*256 + w*64 + CT*16 + c] = acc[RT][CT][r];
      }
  }
}

// ---------------- quantile(r, 0.95): single cooperative launch, 2x 4096-bin radix passes ----------------
// Pass1 bins bits[31:20], pass2 bits[19:8] (same 24-bit precision as old 3x256 passes).
// tl staged ONCE; block 0 scans between passes behind grid.sync().
__global__ __launch_bounds__(256) void k_quant(const float* __restrict__ t_in,
    const float* __restrict__ R_in, unsigned* __restrict__ hist,
    unsigned* __restrict__ state, float* __restrict__ rend){
  cg::grid_group grid = cg::this_grid();
  __shared__ unsigned lh[4096];
  __shared__ float tl[N_][3];
  __shared__ unsigned csum[256];
  int tid = threadIdx.x;
  int row0 = blockIdx.x * 8;
  int b = row0 >> 11;
  for(int e = tid; e < N_*3; e += 256) tl[e/3][e%3] = t_in[(size_t)b*N_*3 + e];
  if(blockIdx.x == 0){
    #pragma unroll
    for(int k = 0; k < 16; k++) hist[tid*16 + k] = 0u;
    if(tid == 0){ state[0] = 0u; state[1] = 7969177u; }
  }
  float Rr[8][9];
  for(int rr = 0; rr < 8; rr++)
    #pragma unroll
    for(int e = 0; e < 9; e++) Rr[rr][e] = R_in[(size_t)(row0+rr)*9 + e];
  __syncthreads();
  grid.sync();

  #pragma unroll
  for(int pass = 0; pass < 2; pass++){
    int shift = pass ? 8 : 20;
    unsigned prefix = state[0];
    for(int e = tid; e < 4096; e += 256) lh[e] = 0u;
    __syncthreads();
    for(int rr = 0; rr < 8; rr++){
      int i = (row0 + rr) & (N_-1);
      float tix = tl[i][0], tiy = tl[i][1], tiz = tl[i][2];
      const float* Rm = Rr[rr];
      for(int j = tid; j < N_; j += 256){
        float dx = tl[j][0]-tix, dy = tl[j][1]-tiy, dz = tl[j][2]-tiz;
        float e0 = Rm[0]*dx + Rm[3]*dy + Rm[6]*dz;
        float e1 = Rm[1]*dx + Rm[4]*dy + Rm[7]*dz;
        float e2 = Rm[2]*dx + Rm[5]*dy + Rm[8]*dz;
        float r = fmaxf(sqrtf(e0*e0 + e1*e1 + e2*e2), 1e-8f);
        unsigned bits = __float_as_uint(r);
        if(pass == 0 || (bits & 0xFFF00000u) == prefix)
          atomicAdd(&lh[(bits >> shift) & 4095u], 1u);
      }
    }
    __syncthreads();
    for(int e = tid; e < 4096; e += 256)
      if(lh[e]) atomicAdd(&hist[e], lh[e]);
    grid.sync();
    if(blockIdx.x == 0){
      unsigned local = 0;
      #pragma unroll
      for(int k = 0; k < 16; k++) local += hist[tid*16 + k];
      csum[tid] = local;
      __syncthreads();
      if(tid == 0){
        unsigned kr = state[1], cum = 0;
        int chunk = 255;
        for(int cc = 0; cc < 256; cc++){
          if(cum + csum[cc] > kr){ chunk = cc; break; }
          cum += csum[cc];
        }
        unsigned sel = chunk*16 + 15;
        for(int k = chunk*16; k < chunk*16 + 16; k++){
          unsigned cc = hist[k];
          if(cum + cc > kr){ sel = (unsigned)k; break; }
          cum += cc;
        }
        state[1] = kr - cum;
        unsigned pre = state[0] | (sel << shift);
        state[0] = pre;
        if(shift == 8) *rend = __uint_as_float(pre) + 1e-6f;
      }
      __syncthreads();
      #pragma unroll
      for(int k = 0; k < 16; k++) hist[tid*16 + k] = 0u;
    }
    grid.sync();
  }
}

// ---------------- per-pair geo -> MLP(20->64->8) bias via MFMA, v5 ----------------
// Lane-parallel geo; LDS geo stride 20 dw (16B-aligned; odd strides corrupt DS b128).
// v5: preload all 4 s-iters' t-coords; hoist the 4 gfrag ds_reads ahead of the tt loop (ILP).
__global__ __launch_bounds__(256,5) void k_biasm(const float* __restrict__ t_in, const float* __restrict__ R_in,
    const float* __restrict__ W1, const float* __restrict__ b1,
    const float* __restrict__ W2, const float* __restrict__ b2,
    const float* __restrict__ rend_p, unsigned short* __restrict__ biasS, int qtr){
  __shared__ __align__(16) unsigned geo[5120];        // 256 rows x 20 dw = 20.5 KB
  __shared__ __align__(16) unsigned hsc[2304];        // 4 waves x 16 rows x 36 dw = 9.2 KB
  int tid = threadIdx.x;
  int wid = tid >> 6, lane = tid & 63, q = lane >> 4, c = lane & 15;
  int bx = blockIdx.x;
  int jh = bx >> 10;
  int b = (bx >> 9) & 1, iq = bx & 511;
  int i = qtr*512 + iq;
  int gi = b*N_ + i;
  const float* tp = t_in + (size_t)b*N_*3;

  union FU { bf16x8 v; unsigned u[4]; };
  FU a1[4];
  #pragma unroll
  for(int T=0;T<4;T++){
    int r0 = T*16 + c;
    float wv[8];
    #pragma unroll
    for(int jj=0;jj<8;jj++){
      int k = q*8 + jj;
      float val = 0.f;
      if(k < 20)       val = W1[r0*20 + k];
      else if(k == 20) val = b1[r0];
      wv[jj] = val;
    }
    a1[T].u[0]=pkw(wv[0],wv[1]); a1[T].u[1]=pkw(wv[2],wv[3]);
    a1[T].u[2]=pkw(wv[4],wv[5]); a1[T].u[3]=pkw(wv[6],wv[7]);
  }
  FU a2[2];
  #pragma unroll
  for(int fr=0;fr<2;fr++){
    float wv[8];
    #pragma unroll
    for(int jj=0;jj<8;jj++){
      int k = fr*32 + q*8 + jj;
      wv[jj] = (c < 8) ? W2[c*64 + k] : 0.f;
    }
    a2[fr].u[0]=pkw(wv[0],wv[1]); a2[fr].u[1]=pkw(wv[2],wv[3]);
    a2[fr].u[2]=pkw(wv[4],wv[5]); a2[fr].u[3]=pkw(wv[6],wv[7]);
  }
  f32x4 binit;
  #pragma unroll
  for(int r=0;r<4;r++) binit[r] = (q < 2) ? b2[q*4 + r] : 0.f;

  float Rm[9];
  #pragma unroll
  for(int e=0;e<9;e++) Rm[e] = R_in[(size_t)gi*9 + e];
  float tix = tp[i*3], tiy = tp[i*3+1], tiz = tp[i*3+2];
  // preload all 4 s-iterations' pair coordinates (issues early, hides L2 latency)
  float tx[4], ty[4], tz[4];
  #pragma unroll
  for(int ss=0; ss<4; ss++){
    int jj = jh*1024 + (wid*4 + ss)*64 + lane;
    tx[ss] = tp[jj*3]; ty[ss] = tp[jj*3+1]; tz[ss] = tp[jj*3+2];
  }
  float s15 = 15.0f / rend_p[0];
  int grow = (wid*64 + lane)*20;
  unsigned short* g16 = (unsigned short*)geo;
  uint4 zq = {0u,0u,0u,0u};
  // constant geo tail (feats 20..31: feat20 = 1.0, rest 0; never dirtied by rbf scatters)
  *(uint2*)&geo[grow + 10] = make_uint2(0x00003F80u, 0u);
  *(uint4*)&geo[grow + 12] = zq;
  size_t orow = ((size_t)b*H_*512 + iq)*2048;       // + head*(512*2048) + j

  for(int s = 0; s < 4; s++){
    int jb = jh*1024 + (wid*4 + s)*64;
    // --- lane-parallel geo for pair j = jb + lane ---
    float dx = tx[s]-tix, dy = ty[s]-tiy, dz = tz[s]-tiz;
    float e0 = Rm[0]*dx + Rm[3]*dy + Rm[6]*dz;
    float e1 = Rm[1]*dx + Rm[4]*dy + Rm[7]*dz;
    float e2 = Rm[2]*dx + Rm[5]*dy + Rm[8]*dz;
    float d2 = e0*e0 + e1*e1 + e2*e2;
    float rr = fmaxf(sqrtf(d2), 1e-8f);
    float ir = __builtin_amdgcn_rcpf(rr);
    float pos = rr * s15;
    float m0f = floorf(pos);
    int   m0  = (int)m0f;
    float w1r = pos - m0f, w0r = 1.0f - w1r;
    uint4 z0; z0.x = pk2(rr, e0*ir); z0.y = pk2(e1*ir, e2*ir); z0.z = 0u; z0.w = 0u;
    *(uint4*)&geo[grow]     = z0;                  // feats 0..7
    *(uint4*)&geo[grow + 4] = zq;                  // feats 8..15 (clear scatter residue)
    *(uint2*)&geo[grow + 8] = make_uint2(0u, 0u);  // feats 16..19
    if(m0 <= 15) g16[grow*2 + 4 + m0] = f2bu(w0r);
    if(m0 <= 14) g16[grow*2 + 5 + m0] = f2bu(w1r);
    // hoisted gfrag reads (same-wave DS ordering guarantees they see the writes above)
    bf16x8 gf[4];
    #pragma unroll
    for(int tt = 0; tt < 4; tt++)
      gf[tt] = *(bf16x8*)&geo[(wid*64 + tt*16 + c)*20 + q*4];
    // --- 4 tiles of 16 pairs ---
    #pragma unroll
    for(int tt = 0; tt < 4; tt++){
      f32x4 d1[4];
      #pragma unroll
      for(int T=0;T<4;T++){
        d1[T] = (f32x4){0.f,0.f,0.f,0.f};
        d1[T] = __builtin_amdgcn_mfma_f32_16x16x32_bf16(a1[T].v, gf[tt], d1[T], 0, 0, 0);
      }
      #pragma unroll
      for(int T=0;T<4;T++){
        uint2 dw;
        dw.x = pk2(fmaxf(d1[T][0],0.f), fmaxf(d1[T][1],0.f));
        dw.y = pk2(fmaxf(d1[T][2],0.f), fmaxf(d1[T][3],0.f));
        *(uint2*)&hsc[wid*576 + c*36 + T*8 + q*2] = dw;
      }
      bf16x8 hb0 = *(bf16x8*)&hsc[wid*576 + c*36 + q*4];
      bf16x8 hb1 = *(bf16x8*)&hsc[wid*576 + c*36 + q*4 + 16];
      f32x4 dv = binit;
      dv = __builtin_amdgcn_mfma_f32_16x16x32_bf16(a2[0].v, hb0, dv, 0, 0, 0);
      dv = __builtin_amdgcn_mfma_f32_16x16x32_bf16(a2[1].v, hb1, dv, 0, 0, 0);
      // direct store: lane (q<2, c) holds bias[head=q*4+r][pair jb+tt*16+c]
      if(q < 2){
        size_t col = orow + (size_t)(jb + tt*16 + c);
        #pragma unroll
        for(int r=0;r<4;r++)
          biasS[col + (size_t)(q*4 + r)*(512*2048)] = f2bu(dv[r]);
      }
    }
  }
}

// ---------------- MFMA flash attention, one i-quarter (bf16 output) ----------------
__global__ __launch_bounds__(512) void k_attn_m(const unsigned short* __restrict__ qb,
    const unsigned short* __restrict__ kb, const unsigned short* __restrict__ vtb,
    const unsigned* __restrict__ biasU, unsigned short* __restrict__ ab, int qtr){
  __shared__ float osc[8][32][16];
  __shared__ float msc[8][16], lsc[8][16];
  __shared__ __align__(16) unsigned ptile[8][320];
  int tid = threadIdx.x;
  int w = tid >> 6, lane = tid & 63, q = lane >> 4, c = lane & 15;
  int bx = blockIdx.x;
  int tile = bx & 31, hh = (bx >> 5) & 7, b = bx >> 8;
  int iqq = tile*16;
  size_t bh = (size_t)b*H_ + hh;
  bf16x8 qfrag = *(const bf16x8*)(qb + (bh*N_ + (size_t)(qtr*512 + iqq + c))*32 + q*8);
  const unsigned short* kbase = kb + bh*N_*32;
  const unsigned short* vbase = vtb + bh*32*N_;
  const unsigned* bbase = biasU + (bh*512 + (size_t)(iqq + c))*1024;

  float m_i = -INFINITY, l_i = 0.f;
  f32x4 oA = {0.f,0.f,0.f,0.f}, oB = {0.f,0.f,0.f,0.f};
  const float SCALE = 0.17677669529663687f;

  int j0 = w*256;
  bf16x8 kf0 = *(const bf16x8*)(kbase + (size_t)(j0 + c)*32 + q*8);
  bf16x8 kf1 = *(const bf16x8*)(kbase + (size_t)(j0 + 16 + c)*32 + q*8);
  bf16x8 vfa = *(const bf16x8*)(vbase + (size_t)c*N_ + j0 + q*8);
  bf16x8 vfb = *(const bf16x8*)(vbase + (size_t)(16 + c)*N_ + j0 + q*8);
  uint2  bd0 = *(const uint2*)(bbase + (j0 >> 1) + q*2);
  uint2  bd1 = *(const uint2*)(bbase + ((j0 + 16) >> 1) + q*2);

  for(int cc = 0; cc < 8; cc++){
    bf16x8 ck0 = kf0, ck1 = kf1, cva = vfa, cvb = vfb;
    uint2 cb0 = bd0, cb1 = bd1;
    int jn = w*256 + ((cc + 1) & 7)*32;
    kf0 = *(const bf16x8*)(kbase + (size_t)(jn + c)*32 + q*8);
    kf1 = *(const bf16x8*)(kbase + (size_t)(jn + 16 + c)*32 + q*8);
    vfa = *(const bf16x8*)(vbase + (size_t)c*N_ + jn + q*8);
    vfb = *(const bf16x8*)(vbase + (size_t)(16 + c)*N_ + jn + q*8);
    bd0 = *(const uint2*)(bbase + (jn >> 1) + q*2);
    bd1 = *(const uint2*)(bbase + ((jn + 16) >> 1) + q*2);

    f32x4 s0 = {0.f,0.f,0.f,0.f}, s1 = {0.f,0.f,0.f,0.f};
    s0 = __builtin_amdgcn_mfma_f32_16x16x32_bf16(ck0, qfrag, s0, 0, 0, 0);
    s1 = __builtin_amdgcn_mfma_f32_16x16x32_bf16(ck1, qfrag, s1, 0, 0, 0);
    float sv[8];
    sv[0] = fmaf(s0[0], SCALE, __uint_as_float(cb0.x << 16));
    sv[1] = fmaf(s0[1], SCALE, __uint_as_float(cb0.x & 0xffff0000u));
    sv[2] = fmaf(s0[2], SCALE, __uint_as_float(cb0.y << 16));
    sv[3] = fmaf(s0[3], SCALE, __uint_as_float(cb0.y & 0xffff0000u));
    sv[4] = fmaf(s1[0], SCALE, __uint_as_float(cb1.x << 16));
    sv[5] = fmaf(s1[1], SCALE, __uint_as_float(cb1.x & 0xffff0000u));
    sv[6] = fmaf(s1[2], SCALE, __uint_as_float(cb1.y << 16));
    sv[7] = fmaf(s1[3], SCALE, __uint_as_float(cb1.y & 0xffff0000u));
    float cmax = sv[0];
    #pragma unroll
    for(int e=1;e<8;e++) cmax = fmaxf(cmax, sv[e]);
    cmax = fmaxf(cmax, __shfl_xor(cmax, 16, 64));
    cmax = fmaxf(cmax, __shfl_xor(cmax, 32, 64));
    float newm = fmaxf(m_i, cmax);
    float alpha = __expf(m_i - newm);
    float p[8], psum = 0.f;
    #pragma unroll
    for(int e=0;e<8;e++){ p[e] = __expf(sv[e] - newm); psum += p[e]; }
    psum += __shfl_xor(psum, 16, 64);
    psum += __shfl_xor(psum, 32, 64);
    l_i = l_i*alpha + psum;
    m_i = newm;
    #pragma unroll
    for(int r=0;r<4;r++){ oA[r] *= alpha; oB[r] *= alpha; }
    uint2 w0; w0.x = pk2(p[0], p[1]); w0.y = pk2(p[2], p[3]);
    uint2 w1; w1.x = pk2(p[4], p[5]); w1.y = pk2(p[6], p[7]);
    *(uint2*)&ptile[w][c*20 + q*2]     = w0;
    *(uint2*)&ptile[w][c*20 + 8 + q*2] = w1;
    bf16x8 pfrag = *(bf16x8*)&ptile[w][c*20 + q*4];
    oA = __builtin_amdgcn_mfma_f32_16x16x32_bf16(cva, pfrag, oA, 0, 0, 0);
    oB = __builtin_amdgcn_mfma_f32_16x16x32_bf16(cvb, pfrag, oB, 0, 0, 0);
  }
  if(q == 0){ msc[w][c] = m_i; lsc[w][c] = l_i; }
  #pragma unroll
  for(int r=0;r<4;r++){
    osc[w][q*4 + r][c]      = oA[r];
    osc[w][16 + q*4 + r][c] = oB[r];
  }
  __syncthreads();
  int mi = tid & 15, md = tid >> 4;
  float M = msc[0][mi];
  #pragma unroll
  for(int ww=1;ww<8;ww++) M = fmaxf(M, msc[ww][mi]);
  float L = 0.f, val = 0.f;
  #pragma unroll
  for(int ww=0;ww<8;ww++){
    float e = __expf(msc[ww][mi] - M);
    L += lsc[ww][mi]*e;
    val += osc[ww][md][mi]*e;
  }
  ab[((size_t)b*N_ + qtr*512 + iqq + mi)*D_ + hh*32 + md] = f2bu(val / L);
}

extern "C" void kernel_launch(void* const* d_in, const int* in_sizes, int n_in,
                              void* d_out, int out_size, void* d_ws, size_t ws_size,
                              hipStream_t stream){
  const float* x  = (const float*)d_in[0];
  const float* R  = (const float*)d_in[1];
  const float* t  = (const float*)d_in[2];
  const float* Wq = (const float*)d_in[4];
  const float* Wk = (const float*)d_in[5];
  const float* Wv = (const float*)d_in[6];
  const float* Wo = (const float*)d_in[7];
  const float* W1 = (const float*)d_in[8];
  const float* b1 = (const float*)d_in[9];
  const float* W2 = (const float*)d_in[10];
  const float* b2 = (const float*)d_in[11];
  float* out = (float*)d_out;

  char* base = (char*)d_ws;
  float* cosT = (float*)base;                                        // 128 KB
  float* sinT = (float*)(base + (1u<<17));                           // 128 KB
  unsigned short* xb = (unsigned short*)(base + (1u<<18));           // 2 MB (1<<20 elems)
  unsigned short* wb = xb + (1u<<20);                                // 512 KB
  unsigned short* qbuf = wb + (1u<<18);                              // 2 MB
  unsigned short* kbuf = qbuf + (1u<<20);                            // 2 MB
  unsigned short* vtb  = kbuf + (1u<<20);                            // 2 MB
  unsigned short* ab   = vtb  + (1u<<20);                            // 2 MB
  char* tail = (char*)(ab + (1u<<20));
  unsigned* state = (unsigned*)tail;
  float*    rend  = (float*)(tail + 64);
  unsigned* hist  = (unsigned*)(tail + 256);                         // 4096 bins = 16 KB
  unsigned* biasU = (unsigned*)(tail + 20480);                       // 33.5 MB quarter slab

  k_prep<<<1408, 256, 0, stream>>>(x, Wq, Wk, Wv, Wo, xb, wb, cosT, sinT);
  k_gemm<<<dim3(64,3), 256, 0, stream>>>(xb, wb, cosT, sinT, qbuf, kbuf, vtb, out, 0);
  {
    void* args[] = {(void*)&t, (void*)&R, (void*)&hist, (void*)&state, (void*)&rend};
    hipLaunchCooperativeKernel((void*)k_quant, dim3(512), dim3(256), args, 0, stream);
  }
  for(int qtr = 0; qtr < 4; qtr++){
    k_biasm<<<2048, 256, 0, stream>>>(t, R, W1, b1, W2, b2, rend, (unsigned short*)biasU, qtr);
    k_attn_m<<<512, 512, 0, stream>>>(qbuf, kbuf, vtb, biasU, ab, qtr);
  }
  k_gemm<<<dim3(64,1), 256, 0, stream>>>(ab, wb, cosT, sinT, qbuf, kbuf, vtb, out, 3);
}

// Round 13
// 426.461 us; speedup vs baseline: 1.5622x; 1.5622x over previous
//
#include <hip/hip_runtime.h>
#include <hip/hip_bf16.h>
#include <math.h>

using bf16 = __hip_bfloat16;

#define B_ 2
#define N_ 2048
#define H_ 8
#define DH_ 32
#define D_ 256

typedef short bf16x8 __attribute__((ext_vector_type(8)));
typedef float f32x4  __attribute__((ext_vector_type(4)));

static __device__ __forceinline__ unsigned short f2bu(float v){
  bf16 b = __float2bfloat16(v);
  unsigned short u; __builtin_memcpy(&u, &b, 2); return u;
}
// pack two floats -> bf16 pair (lo in low16)
static __device__ __forceinline__ unsigned pk2(float lo, float hi){
  return __builtin_amdgcn_perm(__float_as_uint(hi) + 0x8000u,
                               __float_as_uint(lo) + 0x8000u, 0x07060302u);
}
// exact-RNE pack (prologue/weights)
static __device__ __forceinline__ unsigned pkw(float lo, float hi){
  return (unsigned)f2bu(lo) | ((unsigned)f2bu(hi) << 16);
}

// ---------------- fused prep: xcast | wpack | rope tables | hist zero + state init ----------------
__global__ __launch_bounds__(256) void k_prep(const float* __restrict__ x,
    const float* __restrict__ Wq, const float* __restrict__ Wk,
    const float* __restrict__ Wv, const float* __restrict__ Wo,
    unsigned short* __restrict__ xb, unsigned short* __restrict__ wb,
    float* __restrict__ cosT, float* __restrict__ sinT,
    unsigned* __restrict__ hist, unsigned* __restrict__ state){
  int bx = blockIdx.x, tid = threadIdx.x;
  if(bx < 1024){
    size_t g = (size_t)bx*256 + tid;
    float4 f = *(const float4*)(x + g*4);
    uint2 u; u.x = pk2(f.x, f.y); u.y = pk2(f.z, f.w);
    *(uint2*)(xb + g*4) = u;
  } else if(bx < 1280){
    int g = (bx - 1024)*256 + tid;
    int mat = g >> 14;
    int off = (g & 16383) * 4;
    const float* W = (mat==0)?Wq:(mat==1)?Wk:(mat==2)?Wv:Wo;
    float4 f = *(const float4*)(W + off);
    uint2 u; u.x = pkw(f.x, f.y); u.y = pkw(f.z, f.w);
    *(uint2*)(wb + (size_t)mat*65536 + off) = u;
  } else if(bx < 1408){
    int idx = (bx - 1280)*256 + tid;
    int n = idx >> 4, f = idx & 15;
    double invf = exp(-((double)(2*f)/32.0) * log(10000.0));
    double ang = (double)n * invf;
    cosT[idx] = (float)cos(ang);
    sinT[idx] = (float)sin(ang);
  } else {
    hist[(bx - 1408)*256 + tid] = 0u;                     // 16 blocks x 256 = 4096 bins
    if(bx == 1408 && tid == 0){ state[0] = 0u; state[1] = 7969177u; }
  }
}

// ---------------- unified MFMA GEMM (64-row form): 0=Q(RoPE) 1=K(RoPE) 2=V^T 3=proj ----------------
__global__ __launch_bounds__(256) void k_gemm(const unsigned short* __restrict__ a_in,
    const unsigned short* __restrict__ wball, const float* __restrict__ cosT,
    const float* __restrict__ sinT, unsigned short* __restrict__ qb,
    unsigned short* __restrict__ kb, unsigned short* __restrict__ vtb,
    float* __restrict__ fout, int mode_base){
  __shared__ __align__(16) unsigned xs[64*132];
  int tid = threadIdx.x;
  int w = tid >> 6, lane = tid & 63, q = lane >> 4, c = lane & 15;
  int mode = mode_base + blockIdx.y;
  int row0 = blockIdx.x * 64;
  const unsigned short* wbm = wball + (size_t)((mode < 3) ? mode : 3)*65536;
  for(int e = tid; e < 2048; e += 256){
    int row = e >> 5, ch = e & 31;
    uint4 u = *(const uint4*)(a_in + (size_t)(row0+row)*256 + ch*8);
    *(uint4*)&xs[row*132 + ch*4] = u;
  }
  __syncthreads();
  f32x4 acc[4][4];
  #pragma unroll
  for(int a=0;a<4;a++)
    #pragma unroll
    for(int b2=0;b2<4;b2++) acc[a][b2] = (f32x4){0.f,0.f,0.f,0.f};
  for(int kk = 0; kk < 8; kk++){
    bf16x8 af[4], bfr[4];
    #pragma unroll
    for(int RT=0;RT<4;RT++) af[RT] = *(bf16x8*)&xs[(RT*16+c)*132 + kk*16 + q*4];
    #pragma unroll
    for(int CT=0;CT<4;CT++){
      int ocol = w*64 + CT*16 + c;
      bfr[CT] = *(const bf16x8*)(wbm + (size_t)ocol*256 + kk*32 + q*8);
    }
    #pragma unroll
    for(int RT=0;RT<4;RT++)
      #pragma unroll
      for(int CT=0;CT<4;CT++)
        acc[RT][CT] = __builtin_amdgcn_mfma_f32_16x16x32_bf16(af[RT], bfr[CT], acc[RT][CT], 0, 0, 0);
  }
  int bb = row0 >> 11, nloc0 = row0 & (N_-1);
  if(mode < 2){                 // Q or K with RoPE, out [bh][n][dh] bf16
    unsigned short* dst = (mode == 0) ? qb : kb;
    #pragma unroll
    for(int hp = 0; hp < 2; hp++){
      size_t bh = (size_t)bb*H_ + 2*w + hp;
      #pragma unroll
      for(int RT=0;RT<4;RT++)
        #pragma unroll
        for(int r=0;r<4;r++){
          int n = nloc0 + RT*16 + q*4 + r;
          float cs = cosT[n*16 + c], sn = sinT[n*16 + c];
          float d0 = acc[RT][hp*2][r], d1 = acc[RT][hp*2+1][r];
          float n0v = d0*cs - d1*sn;
          float n1v = d1*cs + d0*sn;
          float p0 = __shfl_xor(n0v, 1, 64);
          float p1 = __shfl_xor(n1v, 1, 64);
          if((c & 1) == 0){
            size_t idx = (bh*N_ + n)*32;
            *(unsigned*)(dst + idx + c)      = pk2(n0v, p0);
            *(unsigned*)(dst + idx + 16 + c) = pk2(n1v, p1);
          }
        }
    }
  } else if(mode == 2){         // V transposed: [bh][dh][n] bf16
    #pragma unroll
    for(int CT=0;CT<4;CT++){
      int h = 2*w + (CT>>1), dh = (CT&1)*16 + c;
      size_t basev = ((size_t)(bb*H_ + h)*32 + dh)*N_;
      #pragma unroll
      for(int RT=0;RT<4;RT++){
        int n = nloc0 + RT*16 + q*4;
        uint2 u;
        u.x = pk2(acc[RT][CT][0], acc[RT][CT][1]);
        u.y = pk2(acc[RT][CT][2], acc[RT][CT][3]);
        *(uint2*)(vtb + basev + n) = u;
      }
    }
  } else {                      // proj: fp32 out [row][ocol]
    #pragma unroll
    for(int RT=0;RT<4;RT++)
      #pragma unroll
      for(int r=0;r<4;r++){
        size_t row = (size_t)row0 + RT*16 + q*4 + r;
        #pragma unroll
        for(int CT=0;CT<4;CT++)
          fout[row*256 + w*64 + CT*16 + c] = acc[RT][CT][r];
      }
  }
}

// ---------------- quantile(r,0.95): 2 passes x 4096 bins (bits[31:20], [19:8]) ----------------
// Rm loaded per-row into REGISTERS (r12's Rr[8][9] preload spilled to scratch -> 270us; never again).
__global__ __launch_bounds__(256) void k_qh(const float* __restrict__ t_in,
    const float* __restrict__ R_in, const unsigned* __restrict__ state,
    unsigned* __restrict__ hist, int pass){
  __shared__ unsigned lh[4096];
  __shared__ float tl[N_][3];
  int tid = threadIdx.x;
  int row0 = blockIdx.x * 8;
  int b = row0 >> 11;
  for(int e = tid; e < 4096; e += 256) lh[e] = 0u;
  for(int e = tid; e < N_*3; e += 256) tl[e/3][e%3] = t_in[(size_t)b*N_*3 + e];
  __syncthreads();
  unsigned prefix = state[0];
  for(int rr = 0; rr < 8; rr++){
    int row = row0 + rr;
    int i = row & (N_-1);
    float tix = tl[i][0], tiy = tl[i][1], tiz = tl[i][2];
    float Rm[9];
    #pragma unroll
    for(int e=0;e<9;e++) Rm[e] = R_in[(size_t)row*9 + e];
    for(int j = tid; j < N_; j += 256){
      float dx = tl[j][0]-tix, dy = tl[j][1]-tiy, dz = tl[j][2]-tiz;
      float e0 = Rm[0]*dx + Rm[3]*dy + Rm[6]*dz;
      float e1 = Rm[1]*dx + Rm[4]*dy + Rm[7]*dz;
      float e2 = Rm[2]*dx + Rm[5]*dy + Rm[8]*dz;
      float r = fmaxf(sqrtf(e0*e0 + e1*e1 + e2*e2), 1e-8f);
      unsigned bits = __float_as_uint(r);
      if(pass == 0)
        atomicAdd(&lh[bits >> 20], 1u);
      else if((bits & 0xFFF00000u) == prefix)
        atomicAdd(&lh[(bits >> 8) & 4095u], 1u);
    }
  }
  __syncthreads();
  for(int e = tid; e < 4096; e += 256)
    if(lh[e]) atomicAdd(&hist[e], lh[e]);
}

__global__ void k_qs(unsigned* state, unsigned* hist, int shift, float* rend){
  __shared__ unsigned csum[256];
  int tid = threadIdx.x;
  unsigned local = 0;
  #pragma unroll
  for(int k = 0; k < 16; k++) local += hist[tid*16 + k];
  csum[tid] = local;
  __syncthreads();
  if(tid == 0){
    unsigned kr = state[1], cum = 0;
    int chunk = 255;
    for(int cc = 0; cc < 256; cc++){
      if(cum + csum[cc] > kr){ chunk = cc; break; }
      cum += csum[cc];
    }
    unsigned sel = (unsigned)chunk*16 + 15;
    for(int k = chunk*16; k < chunk*16 + 16; k++){
      unsigned c = hist[k];
      if(cum + c > kr){ sel = (unsigned)k; break; }
      cum += c;
    }
    state[1] = kr - cum;
    unsigned pre = state[0] | (sel << shift);
    state[0] = pre;
    if(shift == 8) *rend = __uint_as_float(pre) + 1e-6f;
  }
  __syncthreads();
  #pragma unroll
  for(int k = 0; k < 16; k++) hist[tid*16 + k] = 0u;  // ready for next pass
}

// ---------------- per-pair geo -> MLP(20->64->8) bias via MFMA, v5 ----------------
__global__ __launch_bounds__(256,5) void k_biasm(const float* __restrict__ t_in, const float* __restrict__ R_in,
    const float* __restrict__ W1, const float* __restrict__ b1,
    const float* __restrict__ W2, const float* __restrict__ b2,
    const float* __restrict__ rend_p, unsigned short* __restrict__ biasS, int qtr){
  __shared__ __align__(16) unsigned geo[5120];        // 256 rows x 20 dw = 20.5 KB
  __shared__ __align__(16) unsigned hsc[2304];        // 4 waves x 16 rows x 36 dw = 9.2 KB
  int tid = threadIdx.x;
  int wid = tid >> 6, lane = tid & 63, q = lane >> 4, c = lane & 15;
  int bx = blockIdx.x;
  int jh = bx >> 10;
  int b = (bx >> 9) & 1, iq = bx & 511;
  int i = qtr*512 + iq;
  int gi = b*N_ + i;
  const float* tp = t_in + (size_t)b*N_*3;

  union FU { bf16x8 v; unsigned u[4]; };
  FU a1[4];
  #pragma unroll
  for(int T=0;T<4;T++){
    int r0 = T*16 + c;
    float wv[8];
    #pragma unroll
    for(int jj=0;jj<8;jj++){
      int k = q*8 + jj;
      float val = 0.f;
      if(k < 20)       val = W1[r0*20 + k];
      else if(k == 20) val = b1[r0];
      wv[jj] = val;
    }
    a1[T].u[0]=pkw(wv[0],wv[1]); a1[T].u[1]=pkw(wv[2],wv[3]);
    a1[T].u[2]=pkw(wv[4],wv[5]); a1[T].u[3]=pkw(wv[6],wv[7]);
  }
  FU a2[2];
  #pragma unroll
  for(int fr=0;fr<2;fr++){
    float wv[8];
    #pragma unroll
    for(int jj=0;jj<8;jj++){
      int k = fr*32 + q*8 + jj;
      wv[jj] = (c < 8) ? W2[c*64 + k] : 0.f;
    }
    a2[fr].u[0]=pkw(wv[0],wv[1]); a2[fr].u[1]=pkw(wv[2],wv[3]);
    a2[fr].u[2]=pkw(wv[4],wv[5]); a2[fr].u[3]=pkw(wv[6],wv[7]);
  }
  f32x4 binit;
  #pragma unroll
  for(int r=0;r<4;r++) binit[r] = (q < 2) ? b2[q*4 + r] : 0.f;

  float Rm[9];
  #pragma unroll
  for(int e=0;e<9;e++) Rm[e] = R_in[(size_t)gi*9 + e];
  float tix = tp[i*3], tiy = tp[i*3+1], tiz = tp[i*3+2];
  float tx[4], ty[4], tz[4];
  #pragma unroll
  for(int ss=0; ss<4; ss++){
    int jj = jh*1024 + (wid*4 + ss)*64 + lane;
    tx[ss] = tp[jj*3]; ty[ss] = tp[jj*3+1]; tz[ss] = tp[jj*3+2];
  }
  float s15 = 15.0f / rend_p[0];
  int grow = (wid*64 + lane)*20;
  unsigned short* g16 = (unsigned short*)geo;
  uint4 zq = {0u,0u,0u,0u};
  *(uint2*)&geo[grow + 10] = make_uint2(0x00003F80u, 0u);
  *(uint4*)&geo[grow + 12] = zq;
  size_t orow = ((size_t)b*H_*512 + iq)*2048;

  for(int s = 0; s < 4; s++){
    int jb = jh*1024 + (wid*4 + s)*64;
    float dx = tx[s]-tix, dy = ty[s]-tiy, dz = tz[s]-tiz;
    float e0 = Rm[0]*dx + Rm[3]*dy + Rm[6]*dz;
    float e1 = Rm[1]*dx + Rm[4]*dy + Rm[7]*dz;
    float e2 = Rm[2]*dx + Rm[5]*dy + Rm[8]*dz;
    float d2 = e0*e0 + e1*e1 + e2*e2;
    float rr = fmaxf(sqrtf(d2), 1e-8f);
    float ir = __builtin_amdgcn_rcpf(rr);
    float pos = rr * s15;
    float m0f = floorf(pos);
    int   m0  = (int)m0f;
    float w1r = pos - m0f, w0r = 1.0f - w1r;
    uint4 z0; z0.x = pk2(rr, e0*ir); z0.y = pk2(e1*ir, e2*ir); z0.z = 0u; z0.w = 0u;
    *(uint4*)&geo[grow]     = z0;
    *(uint4*)&geo[grow + 4] = zq;
    *(uint2*)&geo[grow + 8] = make_uint2(0u, 0u);
    if(m0 <= 15) g16[grow*2 + 4 + m0] = f2bu(w0r);
    if(m0 <= 14) g16[grow*2 + 5 + m0] = f2bu(w1r);
    bf16x8 gf[4];
    #pragma unroll
    for(int tt = 0; tt < 4; tt++)
      gf[tt] = *(bf16x8*)&geo[(wid*64 + tt*16 + c)*20 + q*4];
    #pragma unroll
    for(int tt = 0; tt < 4; tt++){
      f32x4 d1[4];
      #pragma unroll
      for(int T=0;T<4;T++){
        d1[T] = (f32x4){0.f,0.f,0.f,0.f};
        d1[T] = __builtin_amdgcn_mfma_f32_16x16x32_bf16(a1[T].v, gf[tt], d1[T], 0, 0, 0);
      }
      #pragma unroll
      for(int T=0;T<4;T++){
        uint2 dw;
        dw.x = pk2(fmaxf(d1[T][0],0.f), fmaxf(d1[T][1],0.f));
        dw.y = pk2(fmaxf(d1[T][2],0.f), fmaxf(d1[T][3],0.f));
        *(uint2*)&hsc[wid*576 + c*36 + T*8 + q*2] = dw;
      }
      bf16x8 hb0 = *(bf16x8*)&hsc[wid*576 + c*36 + q*4];
      bf16x8 hb1 = *(bf16x8*)&hsc[wid*576 + c*36 + q*4 + 16];
      f32x4 dv = binit;
      dv = __builtin_amdgcn_mfma_f32_16x16x32_bf16(a2[0].v, hb0, dv, 0, 0, 0);
      dv = __builtin_amdgcn_mfma_f32_16x16x32_bf16(a2[1].v, hb1, dv, 0, 0, 0);
      if(q < 2){
        size_t col = orow + (size_t)(jb + tt*16 + c);
        #pragma unroll
        for(int r=0;r<4;r++)
          biasS[col + (size_t)(q*4 + r)*(512*2048)] = f2bu(dv[r]);
      }
    }
  }
}

// ---------------- MFMA flash attention, one i-quarter (bf16 output) ----------------
__global__ __launch_bounds__(512) void k_attn_m(const unsigned short* __restrict__ qb,
    const unsigned short* __restrict__ kb, const unsigned short* __restrict__ vtb,
    const unsigned* __restrict__ biasU, unsigned short* __restrict__ ab, int qtr){
  __shared__ float osc[8][32][16];
  __shared__ float msc[8][16], lsc[8][16];
  __shared__ __align__(16) unsigned ptile[8][320];
  int tid = threadIdx.x;
  int w = tid >> 6, lane = tid & 63, q = lane >> 4, c = lane & 15;
  int bx = blockIdx.x;
  int tile = bx & 31, hh = (bx >> 5) & 7, b = bx >> 8;
  int iqq = tile*16;
  size_t bh = (size_t)b*H_ + hh;
  bf16x8 qfrag = *(const bf16x8*)(qb + (bh*N_ + (size_t)(qtr*512 + iqq + c))*32 + q*8);
  const unsigned short* kbase = kb + bh*N_*32;
  const unsigned short* vbase = vtb + bh*32*N_;
  const unsigned* bbase = biasU + (bh*512 + (size_t)(iqq + c))*1024;

  float m_i = -INFINITY, l_i = 0.f;
  f32x4 oA = {0.f,0.f,0.f,0.f}, oB = {0.f,0.f,0.f,0.f};
  const float SCALE = 0.17677669529663687f;

  int j0 = w*256;
  bf16x8 kf0 = *(const bf16x8*)(kbase + (size_t)(j0 + c)*32 + q*8);
  bf16x8 kf1 = *(const bf16x8*)(kbase + (size_t)(j0 + 16 + c)*32 + q*8);
  bf16x8 vfa = *(const bf16x8*)(vbase + (size_t)c*N_ + j0 + q*8);
  bf16x8 vfb = *(const bf16x8*)(vbase + (size_t)(16 + c)*N_ + j0 + q*8);
  uint2  bd0 = *(const uint2*)(bbase + (j0 >> 1) + q*2);
  uint2  bd1 = *(const uint2*)(bbase + ((j0 + 16) >> 1) + q*2);

  for(int cc = 0; cc < 8; cc++){
    bf16x8 ck0 = kf0, ck1 = kf1, cva = vfa, cvb = vfb;
    uint2 cb0 = bd0, cb1 = bd1;
    int jn = w*256 + ((cc + 1) & 7)*32;
    kf0 = *(const bf16x8*)(kbase + (size_t)(jn + c)*32 + q*8);
    kf1 = *(const bf16x8*)(kbase + (size_t)(jn + 16 + c)*32 + q*8);
    vfa = *(const bf16x8*)(vbase + (size_t)c*N_ + jn + q*8);
    vfb = *(const bf16x8*)(vbase + (size_t)(16 + c)*N_ + jn + q*8);
    bd0 = *(const uint2*)(bbase + (jn >> 1) + q*2);
    bd1 = *(const uint2*)(bbase + ((jn + 16) >> 1) + q*2);

    f32x4 s0 = {0.f,0.f,0.f,0.f}, s1 = {0.f,0.f,0.f,0.f};
    s0 = __builtin_amdgcn_mfma_f32_16x16x32_bf16(ck0, qfrag, s0, 0, 0, 0);
    s1 = __builtin_amdgcn_mfma_f32_16x16x32_bf16(ck1, qfrag, s1, 0, 0, 0);
    float sv[8];
    sv[0] = fmaf(s0[0], SCALE, __uint_as_float(cb0.x << 16));
    sv[1] = fmaf(s0[1], SCALE, __uint_as_float(cb0.x & 0xffff0000u));
    sv[2] = fmaf(s0[2], SCALE, __uint_as_float(cb0.y << 16));
    sv[3] = fmaf(s0[3], SCALE, __uint_as_float(cb0.y & 0xffff0000u));
    sv[4] = fmaf(s1[0], SCALE, __uint_as_float(cb1.x << 16));
    sv[5] = fmaf(s1[1], SCALE, __uint_as_float(cb1.x & 0xffff0000u));
    sv[6] = fmaf(s1[2], SCALE, __uint_as_float(cb1.y << 16));
    sv[7] = fmaf(s1[3], SCALE, __uint_as_float(cb1.y & 0xffff0000u));
    float cmax = sv[0];
    #pragma unroll
    for(int e=1;e<8;e++) cmax = fmaxf(cmax, sv[e]);
    cmax = fmaxf(cmax, __shfl_xor(cmax, 16, 64));
    cmax = fmaxf(cmax, __shfl_xor(cmax, 32, 64));
    float newm = fmaxf(m_i, cmax);
    float alpha = __expf(m_i - newm);
    float p[8], psum = 0.f;
    #pragma unroll
    for(int e=0;e<8;e++){ p[e] = __expf(sv[e] - newm); psum += p[e]; }
    psum += __shfl_xor(psum, 16, 64);
    psum += __shfl_xor(psum, 32, 64);
    l_i = l_i*alpha + psum;
    m_i = newm;
    #pragma unroll
    for(int r=0;r<4;r++){ oA[r] *= alpha; oB[r] *= alpha; }
    uint2 w0; w0.x = pk2(p[0], p[1]); w0.y = pk2(p[2], p[3]);
    uint2 w1; w1.x = pk2(p[4], p[5]); w1.y = pk2(p[6], p[7]);
    *(uint2*)&ptile[w][c*20 + q*2]     = w0;
    *(uint2*)&ptile[w][c*20 + 8 + q*2] = w1;
    bf16x8 pfrag = *(bf16x8*)&ptile[w][c*20 + q*4];
    oA = __builtin_amdgcn_mfma_f32_16x16x32_bf16(cva, pfrag, oA, 0, 0, 0);
    oB = __builtin_amdgcn_mfma_f32_16x16x32_bf16(cvb, pfrag, oB, 0, 0, 0);
  }
  if(q == 0){ msc[w][c] = m_i; lsc[w][c] = l_i; }
  #pragma unroll
  for(int r=0;r<4;r++){
    osc[w][q*4 + r][c]      = oA[r];
    osc[w][16 + q*4 + r][c] = oB[r];
  }
  __syncthreads();
  int mi = tid & 15, md = tid >> 4;
  float M = msc[0][mi];
  #pragma unroll
  for(int ww=1;ww<8;ww++) M = fmaxf(M, msc[ww][mi]);
  float L = 0.f, val = 0.f;
  #pragma unroll
  for(int ww=0;ww<8;ww++){
    float e = __expf(msc[ww][mi] - M);
    L += lsc[ww][mi]*e;
    val += osc[ww][md][mi]*e;
  }
  ab[((size_t)b*N_ + qtr*512 + iqq + mi)*D_ + hh*32 + md] = f2bu(val / L);
}

extern "C" void kernel_launch(void* const* d_in, const int* in_sizes, int n_in,
                              void* d_out, int out_size, void* d_ws, size_t ws_size,
                              hipStream_t stream){
  const float* x  = (const float*)d_in[0];
  const float* R  = (const float*)d_in[1];
  const float* t  = (const float*)d_in[2];
  const float* Wq = (const float*)d_in[4];
  const float* Wk = (const float*)d_in[5];
  const float* Wv = (const float*)d_in[6];
  const float* Wo = (const float*)d_in[7];
  const float* W1 = (const float*)d_in[8];
  const float* b1 = (const float*)d_in[9];
  const float* W2 = (const float*)d_in[10];
  const float* b2 = (const float*)d_in[11];
  float* out = (float*)d_out;

  char* base = (char*)d_ws;
  float* cosT = (float*)base;                                        // 128 KB
  float* sinT = (float*)(base + (1u<<17));                           // 128 KB
  unsigned short* xb = (unsigned short*)(base + (1u<<18));           // 2 MB (1<<20 elems)
  unsigned short* wb = xb + (1u<<20);                                // 512 KB
  unsigned short* qbuf = wb + (1u<<18);                              // 2 MB
  unsigned short* kbuf = qbuf + (1u<<20);                            // 2 MB
  unsigned short* vtb  = kbuf + (1u<<20);                            // 2 MB
  unsigned short* ab   = vtb  + (1u<<20);                            // 2 MB
  char* tail = (char*)(ab + (1u<<20));
  unsigned* state = (unsigned*)tail;
  float*    rend  = (float*)(tail + 64);
  unsigned* hist  = (unsigned*)(tail + 256);                         // 4096 bins = 16 KB
  unsigned* biasU = (unsigned*)(tail + 20480);                       // 33.5 MB quarter slab

  k_prep<<<1424, 256, 0, stream>>>(x, Wq, Wk, Wv, Wo, xb, wb, cosT, sinT, hist, state);
  k_gemm<<<dim3(64,3), 256, 0, stream>>>(xb, wb, cosT, sinT, qbuf, kbuf, vtb, out, 0);
  k_qh<<<512, 256, 0, stream>>>(t, R, state, hist, 0);
  k_qs<<<1, 256, 0, stream>>>(state, hist, 20, rend);
  k_qh<<<512, 256, 0, stream>>>(t, R, state, hist, 1);
  k_qs<<<1, 256, 0, stream>>>(state, hist, 8, rend);
  for(int qtr = 0; qtr < 4; qtr++){
    k_biasm<<<2048, 256, 0, stream>>>(t, R, W1, b1, W2, b2, rend, (unsigned short*)biasU, qtr);
    k_attn_m<<<512, 512, 0, stream>>>(qbuf, kbuf, vtb, biasU, ab, qtr);
  }
  k_gemm<<<dim3(64,1), 256, 0, stream>>>(ab, wb, cosT, sinT, qbuf, kbuf, vtb, out, 3);
}

// Round 14
// 363.621 us; speedup vs baseline: 1.8322x; 1.1728x over previous
//
#include <hip/hip_runtime.h>
#include <hip/hip_bf16.h>
#include <math.h>

using bf16 = __hip_bfloat16;

#define B_ 2
#define N_ 2048
#define H_ 8
#define DH_ 32
#define D_ 256
#define QSLAB ((size_t)16*1024*1024)   // bf16 elems per bias quarter: 2*8*512*2048

typedef short bf16x8 __attribute__((ext_vector_type(8)));
typedef float f32x4  __attribute__((ext_vector_type(4)));

static __device__ __forceinline__ unsigned short f2bu(float v){
  bf16 b = __float2bfloat16(v);
  unsigned short u; __builtin_memcpy(&u, &b, 2); return u;
}
static __device__ __forceinline__ unsigned pk2(float lo, float hi){
  return __builtin_amdgcn_perm(__float_as_uint(hi) + 0x8000u,
                               __float_as_uint(lo) + 0x8000u, 0x07060302u);
}
static __device__ __forceinline__ unsigned pkw(float lo, float hi){
  return (unsigned)f2bu(lo) | ((unsigned)f2bu(hi) << 16);
}

// ---------------- fused prep: xcast | wpack | rope tables | hist zero + state init ----------------
__global__ __launch_bounds__(256) void k_prep(const float* __restrict__ x,
    const float* __restrict__ Wq, const float* __restrict__ Wk,
    const float* __restrict__ Wv, const float* __restrict__ Wo,
    unsigned short* __restrict__ xb, unsigned short* __restrict__ wb,
    float* __restrict__ cosT, float* __restrict__ sinT,
    unsigned* __restrict__ hist, unsigned* __restrict__ state){
  int bx = blockIdx.x, tid = threadIdx.x;
  if(bx < 1024){
    size_t g = (size_t)bx*256 + tid;
    float4 f = *(const float4*)(x + g*4);
    uint2 u; u.x = pk2(f.x, f.y); u.y = pk2(f.z, f.w);
    *(uint2*)(xb + g*4) = u;
  } else if(bx < 1280){
    int g = (bx - 1024)*256 + tid;
    int mat = g >> 14;
    int off = (g & 16383) * 4;
    const float* W = (mat==0)?Wq:(mat==1)?Wk:(mat==2)?Wv:Wo;
    float4 f = *(const float4*)(W + off);
    uint2 u; u.x = pkw(f.x, f.y); u.y = pkw(f.z, f.w);
    *(uint2*)(wb + (size_t)mat*65536 + off) = u;
  } else if(bx < 1408){
    int idx = (bx - 1280)*256 + tid;
    int n = idx >> 4, f = idx & 15;
    double invf = exp(-((double)(2*f)/32.0) * log(10000.0));
    double ang = (double)n * invf;
    cosT[idx] = (float)cos(ang);
    sinT[idx] = (float)sin(ang);
  } else {
    hist[(bx - 1408)*256 + tid] = 0u;
    if(bx == 1408 && tid == 0){ state[0] = 0u; state[1] = 7969177u; }
  }
}

// ---------------- unified MFMA GEMM (64-row form): 0=Q(RoPE) 1=K(RoPE) 2=V^T 3=proj ----------------
__global__ __launch_bounds__(256) void k_gemm(const unsigned short* __restrict__ a_in,
    const unsigned short* __restrict__ wball, const float* __restrict__ cosT,
    const float* __restrict__ sinT, unsigned short* __restrict__ qb,
    unsigned short* __restrict__ kb, unsigned short* __restrict__ vtb,
    float* __restrict__ fout, int mode_base){
  __shared__ __align__(16) unsigned xs[64*132];
  int tid = threadIdx.x;
  int w = tid >> 6, lane = tid & 63, q = lane >> 4, c = lane & 15;
  int mode = mode_base + blockIdx.y;
  int row0 = blockIdx.x * 64;
  const unsigned short* wbm = wball + (size_t)((mode < 3) ? mode : 3)*65536;
  for(int e = tid; e < 2048; e += 256){
    int row = e >> 5, ch = e & 31;
    uint4 u = *(const uint4*)(a_in + (size_t)(row0+row)*256 + ch*8);
    *(uint4*)&xs[row*132 + ch*4] = u;
  }
  __syncthreads();
  f32x4 acc[4][4];
  #pragma unroll
  for(int a=0;a<4;a++)
    #pragma unroll
    for(int b2=0;b2<4;b2++) acc[a][b2] = (f32x4){0.f,0.f,0.f,0.f};
  for(int kk = 0; kk < 8; kk++){
    bf16x8 af[4], bfr[4];
    #pragma unroll
    for(int RT=0;RT<4;RT++) af[RT] = *(bf16x8*)&xs[(RT*16+c)*132 + kk*16 + q*4];
    #pragma unroll
    for(int CT=0;CT<4;CT++){
      int ocol = w*64 + CT*16 + c;
      bfr[CT] = *(const bf16x8*)(wbm + (size_t)ocol*256 + kk*32 + q*8);
    }
    #pragma unroll
    for(int RT=0;RT<4;RT++)
      #pragma unroll
      for(int CT=0;CT<4;CT++)
        acc[RT][CT] = __builtin_amdgcn_mfma_f32_16x16x32_bf16(af[RT], bfr[CT], acc[RT][CT], 0, 0, 0);
  }
  int bb = row0 >> 11, nloc0 = row0 & (N_-1);
  if(mode < 2){                 // Q or K with RoPE, out [bh][n][dh] bf16
    unsigned short* dst = (mode == 0) ? qb : kb;
    #pragma unroll
    for(int hp = 0; hp < 2; hp++){
      size_t bh = (size_t)bb*H_ + 2*w + hp;
      #pragma unroll
      for(int RT=0;RT<4;RT++)
        #pragma unroll
        for(int r=0;r<4;r++){
          int n = nloc0 + RT*16 + q*4 + r;
          float cs = cosT[n*16 + c], sn = sinT[n*16 + c];
          float d0 = acc[RT][hp*2][r], d1 = acc[RT][hp*2+1][r];
          float n0v = d0*cs - d1*sn;
          float n1v = d1*cs + d0*sn;
          float p0 = __shfl_xor(n0v, 1, 64);
          float p1 = __shfl_xor(n1v, 1, 64);
          if((c & 1) == 0){
            size_t idx = (bh*N_ + n)*32;
            *(unsigned*)(dst + idx + c)      = pk2(n0v, p0);
            *(unsigned*)(dst + idx + 16 + c) = pk2(n1v, p1);
          }
        }
    }
  } else if(mode == 2){         // V transposed: [bh][dh][n] bf16
    #pragma unroll
    for(int CT=0;CT<4;CT++){
      int h = 2*w + (CT>>1), dh = (CT&1)*16 + c;
      size_t basev = ((size_t)(bb*H_ + h)*32 + dh)*N_;
      #pragma unroll
      for(int RT=0;RT<4;RT++){
        int n = nloc0 + RT*16 + q*4;
        uint2 u;
        u.x = pk2(acc[RT][CT][0], acc[RT][CT][1]);
        u.y = pk2(acc[RT][CT][2], acc[RT][CT][3]);
        *(uint2*)(vtb + basev + n) = u;
      }
    }
  } else {                      // proj: fp32 out [row][ocol]
    #pragma unroll
    for(int RT=0;RT<4;RT++)
      #pragma unroll
      for(int r=0;r<4;r++){
        size_t row = (size_t)row0 + RT*16 + q*4 + r;
        #pragma unroll
        for(int CT=0;CT<4;CT++)
          fout[row*256 + w*64 + CT*16 + c] = acc[RT][CT][r];
      }
  }
}

// ---------------- quantile(r,0.95): 2 passes x 4096 bins (bits[31:20], [19:8]) ----------------
__global__ __launch_bounds__(256) void k_qh(const float* __restrict__ t_in,
    const float* __restrict__ R_in, const unsigned* __restrict__ state,
    unsigned* __restrict__ hist, int pass){
  __shared__ unsigned lh[4096];
  __shared__ float tl[N_][3];
  int tid = threadIdx.x;
  int row0 = blockIdx.x * 8;
  int b = row0 >> 11;
  for(int e = tid; e < 4096; e += 256) lh[e] = 0u;
  for(int e = tid; e < N_*3; e += 256) tl[e/3][e%3] = t_in[(size_t)b*N_*3 + e];
  __syncthreads();
  unsigned prefix = state[0];
  for(int rr = 0; rr < 8; rr++){
    int row = row0 + rr;
    int i = row & (N_-1);
    float tix = tl[i][0], tiy = tl[i][1], tiz = tl[i][2];
    float Rm[9];
    #pragma unroll
    for(int e=0;e<9;e++) Rm[e] = R_in[(size_t)row*9 + e];
    for(int j = tid; j < N_; j += 256){
      float dx = tl[j][0]-tix, dy = tl[j][1]-tiy, dz = tl[j][2]-tiz;
      float e0 = Rm[0]*dx + Rm[3]*dy + Rm[6]*dz;
      float e1 = Rm[1]*dx + Rm[4]*dy + Rm[7]*dz;
      float e2 = Rm[2]*dx + Rm[5]*dy + Rm[8]*dz;
      float r = fmaxf(sqrtf(e0*e0 + e1*e1 + e2*e2), 1e-8f);
      unsigned bits = __float_as_uint(r);
      if(pass == 0)
        atomicAdd(&lh[bits >> 20], 1u);
      else if((bits & 0xFFF00000u) == prefix)
        atomicAdd(&lh[(bits >> 8) & 4095u], 1u);
    }
  }
  __syncthreads();
  for(int e = tid; e < 4096; e += 256)
    if(lh[e]) atomicAdd(&hist[e], lh[e]);
}

__global__ void k_qs(unsigned* state, unsigned* hist, int shift, float* rend){
  __shared__ unsigned csum[256];
  int tid = threadIdx.x;
  unsigned local = 0;
  #pragma unroll
  for(int k = 0; k < 16; k++) local += hist[tid*16 + k];
  csum[tid] = local;
  __syncthreads();
  if(tid == 0){
    unsigned kr = state[1], cum = 0;
    int chunk = 255;
    for(int cc = 0; cc < 256; cc++){
      if(cum + csum[cc] > kr){ chunk = cc; break; }
      cum += csum[cc];
    }
    unsigned sel = (unsigned)chunk*16 + 15;
    for(int k = chunk*16; k < chunk*16 + 16; k++){
      unsigned c = hist[k];
      if(cum + c > kr){ sel = (unsigned)k; break; }
      cum += c;
    }
    state[1] = kr - cum;
    unsigned pre = state[0] | (sel << shift);
    state[0] = pre;
    if(shift == 8) *rend = __uint_as_float(pre) + 1e-6f;
  }
  __syncthreads();
  #pragma unroll
  for(int k = 0; k < 16; k++) hist[tid*16 + k] = 0u;
}

// ---------------- per-pair geo -> MLP(20->64->8) bias via MFMA, v5 ----------------
// qtr_p >= 0: per-quarter launch (grid 2048), slab = biasS (one quarter).
// qtr_p  < 0: merged launch (grid 8192), qtr = bx>>11, slab = biasS + qtr*QSLAB.
__global__ __launch_bounds__(256,5) void k_biasm(const float* __restrict__ t_in, const float* __restrict__ R_in,
    const float* __restrict__ W1, const float* __restrict__ b1,
    const float* __restrict__ W2, const float* __restrict__ b2,
    const float* __restrict__ rend_p, unsigned short* __restrict__ biasS, int qtr_p){
  __shared__ __align__(16) unsigned geo[5120];
  __shared__ __align__(16) unsigned hsc[2304];
  int tid = threadIdx.x;
  int wid = tid >> 6, lane = tid & 63, q = lane >> 4, c = lane & 15;
  int bxg = blockIdx.x;
  int qtr = (qtr_p >= 0) ? qtr_p : (bxg >> 11);
  if(qtr_p < 0) biasS += (size_t)(bxg >> 11) * QSLAB;
  int bx = bxg & 2047;
  int jh = bx >> 10;
  int b = (bx >> 9) & 1, iq = bx & 511;
  int i = qtr*512 + iq;
  int gi = b*N_ + i;
  const float* tp = t_in + (size_t)b*N_*3;

  union FU { bf16x8 v; unsigned u[4]; };
  FU a1[4];
  #pragma unroll
  for(int T=0;T<4;T++){
    int r0 = T*16 + c;
    float wv[8];
    #pragma unroll
    for(int jj=0;jj<8;jj++){
      int k = q*8 + jj;
      float val = 0.f;
      if(k < 20)       val = W1[r0*20 + k];
      else if(k == 20) val = b1[r0];
      wv[jj] = val;
    }
    a1[T].u[0]=pkw(wv[0],wv[1]); a1[T].u[1]=pkw(wv[2],wv[3]);
    a1[T].u[2]=pkw(wv[4],wv[5]); a1[T].u[3]=pkw(wv[6],wv[7]);
  }
  FU a2[2];
  #pragma unroll
  for(int fr=0;fr<2;fr++){
    float wv[8];
    #pragma unroll
    for(int jj=0;jj<8;jj++){
      int k = fr*32 + q*8 + jj;
      wv[jj] = (c < 8) ? W2[c*64 + k] : 0.f;
    }
    a2[fr].u[0]=pkw(wv[0],wv[1]); a2[fr].u[1]=pkw(wv[2],wv[3]);
    a2[fr].u[2]=pkw(wv[4],wv[5]); a2[fr].u[3]=pkw(wv[6],wv[7]);
  }
  f32x4 binit;
  #pragma unroll
  for(int r=0;r<4;r++) binit[r] = (q < 2) ? b2[q*4 + r] : 0.f;

  float Rm[9];
  #pragma unroll
  for(int e=0;e<9;e++) Rm[e] = R_in[(size_t)gi*9 + e];
  float tix = tp[i*3], tiy = tp[i*3+1], tiz = tp[i*3+2];
  float tx[4], ty[4], tz[4];
  #pragma unroll
  for(int ss=0; ss<4; ss++){
    int jj = jh*1024 + (wid*4 + ss)*64 + lane;
    tx[ss] = tp[jj*3]; ty[ss] = tp[jj*3+1]; tz[ss] = tp[jj*3+2];
  }
  float s15 = 15.0f / rend_p[0];
  int grow = (wid*64 + lane)*20;
  unsigned short* g16 = (unsigned short*)geo;
  uint4 zq = {0u,0u,0u,0u};
  *(uint2*)&geo[grow + 10] = make_uint2(0x00003F80u, 0u);
  *(uint4*)&geo[grow + 12] = zq;
  size_t orow = ((size_t)b*H_*512 + iq)*2048;

  for(int s = 0; s < 4; s++){
    int jb = jh*1024 + (wid*4 + s)*64;
    float dx = tx[s]-tix, dy = ty[s]-tiy, dz = tz[s]-tiz;
    float e0 = Rm[0]*dx + Rm[3]*dy + Rm[6]*dz;
    float e1 = Rm[1]*dx + Rm[4]*dy + Rm[7]*dz;
    float e2 = Rm[2]*dx + Rm[5]*dy + Rm[8]*dz;
    float d2 = e0*e0 + e1*e1 + e2*e2;
    float rr = fmaxf(sqrtf(d2), 1e-8f);
    float ir = __builtin_amdgcn_rcpf(rr);
    float pos = rr * s15;
    float m0f = floorf(pos);
    int   m0  = (int)m0f;
    float w1r = pos - m0f, w0r = 1.0f - w1r;
    uint4 z0; z0.x = pk2(rr, e0*ir); z0.y = pk2(e1*ir, e2*ir); z0.z = 0u; z0.w = 0u;
    *(uint4*)&geo[grow]     = z0;
    *(uint4*)&geo[grow + 4] = zq;
    *(uint2*)&geo[grow + 8] = make_uint2(0u, 0u);
    if(m0 <= 15) g16[grow*2 + 4 + m0] = f2bu(w0r);
    if(m0 <= 14) g16[grow*2 + 5 + m0] = f2bu(w1r);
    bf16x8 gf[4];
    #pragma unroll
    for(int tt = 0; tt < 4; tt++)
      gf[tt] = *(bf16x8*)&geo[(wid*64 + tt*16 + c)*20 + q*4];
    #pragma unroll
    for(int tt = 0; tt < 4; tt++){
      f32x4 d1[4];
      #pragma unroll
      for(int T=0;T<4;T++){
        d1[T] = (f32x4){0.f,0.f,0.f,0.f};
        d1[T] = __builtin_amdgcn_mfma_f32_16x16x32_bf16(a1[T].v, gf[tt], d1[T], 0, 0, 0);
      }
      #pragma unroll
      for(int T=0;T<4;T++){
        uint2 dw;
        dw.x = pk2(fmaxf(d1[T][0],0.f), fmaxf(d1[T][1],0.f));
        dw.y = pk2(fmaxf(d1[T][2],0.f), fmaxf(d1[T][3],0.f));
        *(uint2*)&hsc[wid*576 + c*36 + T*8 + q*2] = dw;
      }
      bf16x8 hb0 = *(bf16x8*)&hsc[wid*576 + c*36 + q*4];
      bf16x8 hb1 = *(bf16x8*)&hsc[wid*576 + c*36 + q*4 + 16];
      f32x4 dv = binit;
      dv = __builtin_amdgcn_mfma_f32_16x16x32_bf16(a2[0].v, hb0, dv, 0, 0, 0);
      dv = __builtin_amdgcn_mfma_f32_16x16x32_bf16(a2[1].v, hb1, dv, 0, 0, 0);
      if(q < 2){
        size_t col = orow + (size_t)(jb + tt*16 + c);
        #pragma unroll
        for(int r=0;r<4;r++)
          biasS[col + (size_t)(q*4 + r)*(512*2048)] = f2bu(dv[r]);
      }
    }
  }
}

// ---------------- MFMA flash attention (bf16 output) ----------------
// XCD-aware block map: bhid = bx&15 -> all 32 tiles of one (b,h) share bx mod 8 (same XCD
// under round-robin dispatch) -> 512 KB K/V working set stays L2-resident. Heuristic only.
// qtr_p >= 0: per-quarter launch (grid 512). qtr_p < 0: merged (grid 2048), qtr = bx>>9,
// bias slab offset qtr*QSLAB/2 dwords.
__global__ __launch_bounds__(512) void k_attn_m(const unsigned short* __restrict__ qb,
    const unsigned short* __restrict__ kb, const unsigned short* __restrict__ vtb,
    const unsigned* __restrict__ biasU, unsigned short* __restrict__ ab, int qtr_p){
  __shared__ float osc[8][32][16];
  __shared__ float msc[8][16], lsc[8][16];
  __shared__ __align__(16) unsigned ptile[8][320];
  int tid = threadIdx.x;
  int w = tid >> 6, lane = tid & 63, q = lane >> 4, c = lane & 15;
  int bxg = blockIdx.x;
  int qtr = (qtr_p >= 0) ? qtr_p : (bxg >> 9);
  if(qtr_p < 0) biasU += (size_t)(bxg >> 9) * (QSLAB/2);
  int bx = bxg & 511;
  int bhid = bx & 15, tile = bx >> 4;
  int hh = bhid & 7, b = bhid >> 3;
  int iqq = tile*16;
  size_t bh = (size_t)b*H_ + hh;
  bf16x8 qfrag = *(const bf16x8*)(qb + (bh*N_ + (size_t)(qtr*512 + iqq + c))*32 + q*8);
  const unsigned short* kbase = kb + bh*N_*32;
  const unsigned short* vbase = vtb + bh*32*N_;
  const unsigned* bbase = biasU + (bh*512 + (size_t)(iqq + c))*1024;

  float m_i = -INFINITY, l_i = 0.f;
  f32x4 oA = {0.f,0.f,0.f,0.f}, oB = {0.f,0.f,0.f,0.f};
  const float SCALE = 0.17677669529663687f;

  int j0 = w*256;
  bf16x8 kf0 = *(const bf16x8*)(kbase + (size_t)(j0 + c)*32 + q*8);
  bf16x8 kf1 = *(const bf16x8*)(kbase + (size_t)(j0 + 16 + c)*32 + q*8);
  bf16x8 vfa = *(const bf16x8*)(vbase + (size_t)c*N_ + j0 + q*8);
  bf16x8 vfb = *(const bf16x8*)(vbase + (size_t)(16 + c)*N_ + j0 + q*8);
  uint2  bd0 = *(const uint2*)(bbase + (j0 >> 1) + q*2);
  uint2  bd1 = *(const uint2*)(bbase + ((j0 + 16) >> 1) + q*2);

  for(int cc = 0; cc < 8; cc++){
    bf16x8 ck0 = kf0, ck1 = kf1, cva = vfa, cvb = vfb;
    uint2 cb0 = bd0, cb1 = bd1;
    int jn = w*256 + ((cc + 1) & 7)*32;
    kf0 = *(const bf16x8*)(kbase + (size_t)(jn + c)*32 + q*8);
    kf1 = *(const bf16x8*)(kbase + (size_t)(jn + 16 + c)*32 + q*8);
    vfa = *(const bf16x8*)(vbase + (size_t)c*N_ + jn + q*8);
    vfb = *(const bf16x8*)(vbase + (size_t)(16 + c)*N_ + jn + q*8);
    bd0 = *(const uint2*)(bbase + (jn >> 1) + q*2);
    bd1 = *(const uint2*)(bbase + ((jn + 16) >> 1) + q*2);

    f32x4 s0 = {0.f,0.f,0.f,0.f}, s1 = {0.f,0.f,0.f,0.f};
    s0 = __builtin_amdgcn_mfma_f32_16x16x32_bf16(ck0, qfrag, s0, 0, 0, 0);
    s1 = __builtin_amdgcn_mfma_f32_16x16x32_bf16(ck1, qfrag, s1, 0, 0, 0);
    float sv[8];
    sv[0] = fmaf(s0[0], SCALE, __uint_as_float(cb0.x << 16));
    sv[1] = fmaf(s0[1], SCALE, __uint_as_float(cb0.x & 0xffff0000u));
    sv[2] = fmaf(s0[2], SCALE, __uint_as_float(cb0.y << 16));
    sv[3] = fmaf(s0[3], SCALE, __uint_as_float(cb0.y & 0xffff0000u));
    sv[4] = fmaf(s1[0], SCALE, __uint_as_float(cb1.x << 16));
    sv[5] = fmaf(s1[1], SCALE, __uint_as_float(cb1.x & 0xffff0000u));
    sv[6] = fmaf(s1[2], SCALE, __uint_as_float(cb1.y << 16));
    sv[7] = fmaf(s1[3], SCALE, __uint_as_float(cb1.y & 0xffff0000u));
    float cmax = sv[0];
    #pragma unroll
    for(int e=1;e<8;e++) cmax = fmaxf(cmax, sv[e]);
    cmax = fmaxf(cmax, __shfl_xor(cmax, 16, 64));
    cmax = fmaxf(cmax, __shfl_xor(cmax, 32, 64));
    float newm = fmaxf(m_i, cmax);
    float alpha = __expf(m_i - newm);
    float p[8], psum = 0.f;
    #pragma unroll
    for(int e=0;e<8;e++){ p[e] = __expf(sv[e] - newm); psum += p[e]; }
    psum += __shfl_xor(psum, 16, 64);
    psum += __shfl_xor(psum, 32, 64);
    l_i = l_i*alpha + psum;
    m_i = newm;
    #pragma unroll
    for(int r=0;r<4;r++){ oA[r] *= alpha; oB[r] *= alpha; }
    uint2 w0; w0.x = pk2(p[0], p[1]); w0.y = pk2(p[2], p[3]);
    uint2 w1; w1.x = pk2(p[4], p[5]); w1.y = pk2(p[6], p[7]);
    *(uint2*)&ptile[w][c*20 + q*2]     = w0;
    *(uint2*)&ptile[w][c*20 + 8 + q*2] = w1;
    bf16x8 pfrag = *(bf16x8*)&ptile[w][c*20 + q*4];
    oA = __builtin_amdgcn_mfma_f32_16x16x32_bf16(cva, pfrag, oA, 0, 0, 0);
    oB = __builtin_amdgcn_mfma_f32_16x16x32_bf16(cvb, pfrag, oB, 0, 0, 0);
  }
  if(q == 0){ msc[w][c] = m_i; lsc[w][c] = l_i; }
  #pragma unroll
  for(int r=0;r<4;r++){
    osc[w][q*4 + r][c]      = oA[r];
    osc[w][16 + q*4 + r][c] = oB[r];
  }
  __syncthreads();
  int mi = tid & 15, md = tid >> 4;
  float M = msc[0][mi];
  #pragma unroll
  for(int ww=1;ww<8;ww++) M = fmaxf(M, msc[ww][mi]);
  float L = 0.f, val = 0.f;
  #pragma unroll
  for(int ww=0;ww<8;ww++){
    float e = __expf(msc[ww][mi] - M);
    L += lsc[ww][mi]*e;
    val += osc[ww][md][mi]*e;
  }
  ab[((size_t)b*N_ + qtr*512 + iqq + mi)*D_ + hh*32 + md] = f2bu(val / L);
}

extern "C" void kernel_launch(void* const* d_in, const int* in_sizes, int n_in,
                              void* d_out, int out_size, void* d_ws, size_t ws_size,
                              hipStream_t stream){
  const float* x  = (const float*)d_in[0];
  const float* R  = (const float*)d_in[1];
  const float* t  = (const float*)d_in[2];
  const float* Wq = (const float*)d_in[4];
  const float* Wk = (const float*)d_in[5];
  const float* Wv = (const float*)d_in[6];
  const float* Wo = (const float*)d_in[7];
  const float* W1 = (const float*)d_in[8];
  const float* b1 = (const float*)d_in[9];
  const float* W2 = (const float*)d_in[10];
  const float* b2 = (const float*)d_in[11];
  float* out = (float*)d_out;

  char* base = (char*)d_ws;
  float* cosT = (float*)base;
  float* sinT = (float*)(base + (1u<<17));
  unsigned short* xb = (unsigned short*)(base + (1u<<18));
  unsigned short* wb = xb + (1u<<20);
  unsigned short* qbuf = wb + (1u<<18);
  unsigned short* kbuf = qbuf + (1u<<20);
  unsigned short* vtb  = kbuf + (1u<<20);
  unsigned short* ab   = vtb  + (1u<<20);
  char* tail = (char*)(ab + (1u<<20));
  unsigned* state = (unsigned*)tail;
  float*    rend  = (float*)(tail + 64);
  unsigned* hist  = (unsigned*)(tail + 256);
  unsigned short* biasS = (unsigned short*)(tail + 20480);
  size_t used_base = (size_t)((char*)biasS - base);
  bool full = ws_size >= used_base + 4*QSLAB*sizeof(unsigned short) + 4096;

  k_prep<<<1424, 256, 0, stream>>>(x, Wq, Wk, Wv, Wo, xb, wb, cosT, sinT, hist, state);
  k_gemm<<<dim3(64,3), 256, 0, stream>>>(xb, wb, cosT, sinT, qbuf, kbuf, vtb, out, 0);
  k_qh<<<512, 256, 0, stream>>>(t, R, state, hist, 0);
  k_qs<<<1, 256, 0, stream>>>(state, hist, 20, rend);
  k_qh<<<512, 256, 0, stream>>>(t, R, state, hist, 1);
  k_qs<<<1, 256, 0, stream>>>(state, hist, 8, rend);
  if(full){
    k_biasm<<<8192, 256, 0, stream>>>(t, R, W1, b1, W2, b2, rend, biasS, -1);
    k_attn_m<<<2048, 512, 0, stream>>>(qbuf, kbuf, vtb, (unsigned*)biasS, ab, -1);
  } else {
    for(int qtr = 0; qtr < 4; qtr++){
      k_biasm<<<2048, 256, 0, stream>>>(t, R, W1, b1, W2, b2, rend, biasS, qtr);
      k_attn_m<<<512, 512, 0, stream>>>(qbuf, kbuf, vtb, (unsigned*)biasS, ab, qtr);
    }
  }
  k_gemm<<<dim3(64,1), 256, 0, stream>>>(ab, wb, cosT, sinT, qbuf, kbuf, vtb, out, 3);
}